// Round 1
// baseline (423.803 us; speedup 1.0000x reference)
//
#include <hip/hip_runtime.h>

// GRU final-hidden: B=8192 sequences, T=2048 steps, I=1, H=3.
// One thread per batch element; entire recurrence in registers.
// out[b*3+i] = sigmoid(h_T[b][i]).

#define LOG2E 1.4426950408889634f

__device__ __forceinline__ float fexp2(float a) { return __builtin_amdgcn_exp2f(a); }
__device__ __forceinline__ float frcp(float a)  { return __builtin_amdgcn_rcpf(a); }
// sigmoid(a) = 1/(1+exp(-a)) = rcp(1 + exp2(-a*log2e))
__device__ __forceinline__ float sigm(float a)  { return frcp(fexp2(-LOG2E * a) + 1.0f); }
// tanh(u) = 1 - 2/(exp(2u)+1) = 1 - 2*rcp(1 + exp2(2*log2e*u))
__device__ __forceinline__ float tanh_(float a) { return fmaf(-2.0f, frcp(fexp2(2.0f * LOG2E * a) + 1.0f), 1.0f); }

__global__ __launch_bounds__(64) void gru_scan(
    const float* __restrict__ x,      // [B,T] (I=1)
    const int*   __restrict__ lens,   // [B]
    const float* __restrict__ h0,     // [B,3]
    const float* __restrict__ W_ih,   // [9,1]
    const float* __restrict__ W_hh,   // [9,3]
    const float* __restrict__ b_ih,   // [9]
    const float* __restrict__ b_hh,   // [9]
    float*       __restrict__ out,    // [B,3]
    int B, int T)
{
    const int b = blockIdx.x * 64 + threadIdx.x;
    if (b >= B) return;

    // ---- uniform weights (compiler should scalarize these loads) ----
    float wih[9], whh[27], cb[6], bni[3], bnh[3];
#pragma unroll
    for (int g = 0; g < 9; ++g)  wih[g] = W_ih[g];
#pragma unroll
    for (int g = 0; g < 27; ++g) whh[g] = W_hh[g];
#pragma unroll
    for (int g = 0; g < 6; ++g)  cb[g] = b_ih[g] + b_hh[g];   // r,z gates: biases fold
#pragma unroll
    for (int i = 0; i < 3; ++i)  { bni[i] = b_ih[6 + i]; bnh[i] = b_hh[6 + i]; } // n gate: kept apart (r multiplies b_hh_n)

    float hv0 = h0[b * 3 + 0];
    float hv1 = h0[b * 3 + 1];
    float hv2 = h0[b * 3 + 2];

    const int len = lens[b];
    // wave-wide max length, rounded up to multiple of 4
    int wmax = len;
#pragma unroll
    for (int off = 32; off >= 1; off >>= 1)
        wmax = max(wmax, __shfl_xor(wmax, off));
    wmax = (wmax + 3) & ~3;

    const float* xp = x + (long long)b * T;
    float4 cur = *reinterpret_cast<const float4*>(xp);

    for (int t0 = 0; t0 < wmax; t0 += 4) {
        // prefetch next 4 inputs (clamped so the last batch row never over-reads)
        int tn = t0 + 4; if (tn > T - 4) tn = T - 4;
        float4 nxt = *reinterpret_cast<const float4*>(xp + tn);

#pragma unroll
        for (int k = 0; k < 4; ++k) {
            const float xs = (k == 0) ? cur.x : (k == 1) ? cur.y : (k == 2) ? cur.z : cur.w;

            float r[3], z[3], nn[3];
#pragma unroll
            for (int i = 0; i < 3; ++i) {
                float a = fmaf(xs, wih[i], cb[i]);
                a = fmaf(whh[3 * i + 0], hv0, a);
                a = fmaf(whh[3 * i + 1], hv1, a);
                a = fmaf(whh[3 * i + 2], hv2, a);
                r[i] = sigm(a);
            }
#pragma unroll
            for (int i = 0; i < 3; ++i) {
                float a = fmaf(xs, wih[3 + i], cb[3 + i]);
                a = fmaf(whh[3 * (3 + i) + 0], hv0, a);
                a = fmaf(whh[3 * (3 + i) + 1], hv1, a);
                a = fmaf(whh[3 * (3 + i) + 2], hv2, a);
                z[i] = sigm(a);
            }
#pragma unroll
            for (int i = 0; i < 3; ++i) {
                float an = fmaf(xs, wih[6 + i], bni[i]);
                float hg = fmaf(whh[3 * (6 + i) + 0], hv0, bnh[i]);
                hg = fmaf(whh[3 * (6 + i) + 1], hv1, hg);
                hg = fmaf(whh[3 * (6 + i) + 2], hv2, hg);
                nn[i] = tanh_(fmaf(r[i], hg, an));
            }
            // h = n + z*(h - n)
            const float nh0 = fmaf(z[0], hv0 - nn[0], nn[0]);
            const float nh1 = fmaf(z[1], hv1 - nn[1], nn[1]);
            const float nh2 = fmaf(z[2], hv2 - nn[2], nn[2]);
            const bool upd = (t0 + k) < len;
            hv0 = upd ? nh0 : hv0;
            hv1 = upd ? nh1 : hv1;
            hv2 = upd ? nh2 : hv2;
        }
        cur = nxt;
    }

    out[b * 3 + 0] = sigm(hv0);
    out[b * 3 + 1] = sigm(hv1);
    out[b * 3 + 2] = sigm(hv2);
}

extern "C" void kernel_launch(void* const* d_in, const int* in_sizes, int n_in,
                              void* d_out, int out_size, void* d_ws, size_t ws_size,
                              hipStream_t stream) {
    const float* x    = (const float*)d_in[0];
    const int*   lens = (const int*)  d_in[1];
    const float* h0   = (const float*)d_in[2];
    const float* W_ih = (const float*)d_in[3];
    const float* W_hh = (const float*)d_in[4];
    const float* b_ih = (const float*)d_in[5];
    const float* b_hh = (const float*)d_in[6];
    float* out = (float*)d_out;

    const int B = in_sizes[1];              // seq_lengths is [B]
    const int T = in_sizes[0] / B;          // x is [B,T,1]

    gru_scan<<<B / 64, 64, 0, stream>>>(x, lens, h0, W_ih, W_hh, b_ih, b_hh, out, B, T);
}

// Round 2
// 195.024 us; speedup vs baseline: 2.1731x; 2.1731x over previous
//
#include <hip/hip_runtime.h>

// GRU final-hidden: B=8192, T=2048, I=1, H=3.
// R2: 4 lanes per batch (one hidden component per lane; lane 3 duplicates lane 2).
// 16 batches per wave -> 512 waves -> one wave per SIMD on most of the chip.
// Cross-lane h broadcast each step via DPP quad_perm (VALU-only, no LDS).

#define LOG2E 1.4426950408889634f

__device__ __forceinline__ float fexp2(float a) { return __builtin_amdgcn_exp2f(a); }
__device__ __forceinline__ float frcp(float a)  { return __builtin_amdgcn_rcpf(a); }
// sigmoid(a) = rcp(1 + exp2(-a*log2e))
__device__ __forceinline__ float sigm(float a)  { return frcp(fexp2(-LOG2E * a) + 1.0f); }
// tanh(u) = 1 - 2*rcp(1 + exp2(2*log2e*u))
__device__ __forceinline__ float tanh_(float a) { return fmaf(-2.0f, frcp(fexp2(2.0f * LOG2E * a) + 1.0f), 1.0f); }

// broadcast lane (base_of_quad + SRC) to all 4 lanes of the quad, VALU-only
#define QBCAST(x, CTRL) __builtin_bit_cast(float, \
    __builtin_amdgcn_mov_dpp(__builtin_bit_cast(int, (x)), (CTRL), 0xF, 0xF, true))

__global__ __launch_bounds__(64) void gru_scan4(
    const float* __restrict__ x,      // [B,T] (I=1)
    const int*   __restrict__ lens,   // [B]
    const float* __restrict__ h0,     // [B,3]
    const float* __restrict__ W_ih,   // [9,1]
    const float* __restrict__ W_hh,   // [9,3]
    const float* __restrict__ b_ih,   // [9]
    const float* __restrict__ b_hh,   // [9]
    float*       __restrict__ out,    // [B,3]
    int B, int T)
{
    const int lane = threadIdx.x;          // block = 64 = one wave
    const int g    = lane >> 2;            // group (batch slot) 0..15
    const int j    = lane & 3;             // component lane
    const int je   = j < 2 ? j : 2;        // lane 3 duplicates component 2
    const int batch = blockIdx.x * 16 + g;

    // ---- per-lane weights for component je (one-time loads, L2-hot) ----
    const float wxr = W_ih[je],     wxz = W_ih[3 + je], wxn = W_ih[6 + je];
    const float wr0 = W_hh[je * 3 + 0], wr1 = W_hh[je * 3 + 1], wr2 = W_hh[je * 3 + 2];
    const float wz0 = W_hh[(3 + je) * 3 + 0], wz1 = W_hh[(3 + je) * 3 + 1], wz2 = W_hh[(3 + je) * 3 + 2];
    const float wn0 = W_hh[(6 + je) * 3 + 0], wn1 = W_hh[(6 + je) * 3 + 1], wn2 = W_hh[(6 + je) * 3 + 2];
    const float cbr = b_ih[je] + b_hh[je];
    const float cbz = b_ih[3 + je] + b_hh[3 + je];
    const float bni = b_ih[6 + je];
    const float bnh = b_hh[6 + je];

    float h = h0[batch * 3 + je];
    const int len = lens[batch];

    // wave-wide max length (16 batches), rounded up to multiple of 4
    int wmax = len;
#pragma unroll
    for (int off = 32; off >= 1; off >>= 1)
        wmax = max(wmax, __shfl_xor(wmax, off));
    wmax = (wmax + 3) & ~3;

    const float* xp = x + (long long)batch * T;
    float4 cur = *reinterpret_cast<const float4*>(xp);

    for (int t0 = 0; t0 < wmax; t0 += 4) {
        int tn = t0 + 4; if (tn > T - 4) tn = T - 4;
        float4 nxt = *reinterpret_cast<const float4*>(xp + tn);

#pragma unroll
        for (int k = 0; k < 4; ++k) {
            const float xs = (k == 0) ? cur.x : (k == 1) ? cur.y : (k == 2) ? cur.z : cur.w;

            // gather the quad's hidden state (components 0,1,2)
            const float h0g = QBCAST(h, 0x00);   // lane0's h
            const float h1g = QBCAST(h, 0x55);   // lane1's h
            const float h2g = QBCAST(h, 0xAA);   // lane2's h

            float ar = fmaf(xs, wxr, cbr);
            ar = fmaf(wr0, h0g, ar); ar = fmaf(wr1, h1g, ar); ar = fmaf(wr2, h2g, ar);
            float az = fmaf(xs, wxz, cbz);
            az = fmaf(wz0, h0g, az); az = fmaf(wz1, h1g, az); az = fmaf(wz2, h2g, az);
            float hg = fmaf(wn0, h0g, bnh);
            hg = fmaf(wn1, h1g, hg); hg = fmaf(wn2, h2g, hg);

            const float r = sigm(ar);
            const float z = sigm(az);
            const float n = tanh_(fmaf(r, hg, fmaf(xs, wxn, bni)));

            const float hn = fmaf(z, h - n, n);
            h = ((t0 + k) < len) ? hn : h;
        }
        cur = nxt;
    }

    if (j < 3)
        out[batch * 3 + j] = sigm(h);
}

extern "C" void kernel_launch(void* const* d_in, const int* in_sizes, int n_in,
                              void* d_out, int out_size, void* d_ws, size_t ws_size,
                              hipStream_t stream) {
    const float* x    = (const float*)d_in[0];
    const int*   lens = (const int*)  d_in[1];
    const float* h0   = (const float*)d_in[2];
    const float* W_ih = (const float*)d_in[3];
    const float* W_hh = (const float*)d_in[4];
    const float* b_ih = (const float*)d_in[5];
    const float* b_hh = (const float*)d_in[6];
    float* out = (float*)d_out;

    const int B = in_sizes[1];              // seq_lengths is [B]
    const int T = in_sizes[0] / B;          // x is [B,T,1]

    gru_scan4<<<B / 16, 64, 0, stream>>>(x, lens, h0, W_ih, W_hh, b_ih, b_hh, out, B, T);
}

// Round 3
// 168.516 us; speedup vs baseline: 2.5149x; 1.1573x over previous
//
#include <hip/hip_runtime.h>

// GRU final-hidden: B=8192, T=2048, I=1, H=3.
// R3: quad-per-batch (as R2) + 16-step-deep x prefetch (HBM latency ~900cyc
// was the R2 floor) + log2e folded into weights + off-chain length save.

#define NL (-1.4426950408889634f)   // -log2(e): sigmoid(a)=rcp(1+exp2(NL*a))
#define TL ( 2.8853900817779268f)   // 2*log2(e): tanh(u)=1-2*rcp(1+exp2(TL*u))

__device__ __forceinline__ float fexp2(float a) { return __builtin_amdgcn_exp2f(a); }
__device__ __forceinline__ float frcp(float a)  { return __builtin_amdgcn_rcpf(a); }

// broadcast quad-lane SRC to all 4 lanes (VALU-only)
#define QB(x, CTRL) __builtin_bit_cast(float, \
    __builtin_amdgcn_mov_dpp(__builtin_bit_cast(int, (x)), (CTRL), 0xF, 0xF, true))

__global__ __launch_bounds__(64) void gru_scan8(
    const float* __restrict__ x,      // [B,T] (I=1)
    const int*   __restrict__ lens,   // [B]
    const float* __restrict__ h0,     // [B,3]
    const float* __restrict__ W_ih,   // [9,1]
    const float* __restrict__ W_hh,   // [9,3]
    const float* __restrict__ b_ih,   // [9]
    const float* __restrict__ b_hh,   // [9]
    float*       __restrict__ out,    // [B,3]
    int B, int T)
{
    const int lane = threadIdx.x;          // block = 1 wave
    const int g    = lane >> 2;            // batch slot 0..15
    const int j    = lane & 3;             // component lane
    const int je   = j < 2 ? j : 2;        // lane 3 duplicates component 2
    const int batch = blockIdx.x * 16 + g;

    // per-lane weights, pre-scaled so exp2 args come straight off the FMA chain
    const float wxr = NL * W_ih[je], wxz = NL * W_ih[3 + je], wxn = TL * W_ih[6 + je];
    const float wr0 = NL * W_hh[je * 3 + 0], wr1 = NL * W_hh[je * 3 + 1], wr2 = NL * W_hh[je * 3 + 2];
    const float wz0 = NL * W_hh[(3 + je) * 3 + 0], wz1 = NL * W_hh[(3 + je) * 3 + 1], wz2 = NL * W_hh[(3 + je) * 3 + 2];
    const float wn0 = TL * W_hh[(6 + je) * 3 + 0], wn1 = TL * W_hh[(6 + je) * 3 + 1], wn2 = TL * W_hh[(6 + je) * 3 + 2];
    const float cbr = NL * (b_ih[je] + b_hh[je]);
    const float cbz = NL * (b_ih[3 + je] + b_hh[3 + je]);
    const float bni = TL * b_ih[6 + je];
    const float bnh = TL * b_hh[6 + je];

    float h  = h0[batch * 3 + je];
    float hs = h;                          // h saved at t == len-1
    const int len = lens[batch];

    int wmax = len;
#pragma unroll
    for (int off = 32; off >= 1; off >>= 1)
        wmax = max(wmax, __shfl_xor(wmax, off));
    wmax = (wmax + 7) & ~7;

    const float* xp = x + (long long)batch * T;
    // 16-step-deep prefetch pipeline: cur (this iter), nb (next iter), +2 issued in loop
    float4 c0 = *reinterpret_cast<const float4*>(xp + 0);
    float4 c1 = *reinterpret_cast<const float4*>(xp + 4);
    int t1 = 8  > T - 8 ? T - 8 : 8;
    float4 n0 = *reinterpret_cast<const float4*>(xp + t1);
    float4 n1 = *reinterpret_cast<const float4*>(xp + t1 + 4);

    for (int t0 = 0; t0 < wmax; t0 += 8) {
        int ta = t0 + 16; if (ta > T - 8) ta = T - 8;   // 2 iters ahead
        float4 f0 = *reinterpret_cast<const float4*>(xp + ta);
        float4 f1 = *reinterpret_cast<const float4*>(xp + ta + 4);

        const float xs[8] = {c0.x, c0.y, c0.z, c0.w, c1.x, c1.y, c1.z, c1.w};
        float bxr[8], bxz[8], bxn[8];
#pragma unroll
        for (int k = 0; k < 8; ++k) {
            bxr[k] = fmaf(xs[k], wxr, cbr);
            bxz[k] = fmaf(xs[k], wxz, cbz);
            bxn[k] = fmaf(xs[k], wxn, bni);
        }
#pragma unroll
        for (int k = 0; k < 8; ++k) {
            const float h0g = QB(h, 0x00);
            const float h1g = QB(h, 0x55);
            const float h2g = QB(h, 0xAA);

            float ar = fmaf(wr0, h0g, bxr[k]); ar = fmaf(wr1, h1g, ar); ar = fmaf(wr2, h2g, ar);
            float az = fmaf(wz0, h0g, bxz[k]); az = fmaf(wz1, h1g, az); az = fmaf(wz2, h2g, az);
            float hg = fmaf(wn0, h0g, bnh);    hg = fmaf(wn1, h1g, hg); hg = fmaf(wn2, h2g, hg);

            const float r = frcp(fexp2(ar) + 1.0f);
            const float z = frcp(fexp2(az) + 1.0f);
            const float v = fmaf(r, hg, bxn[k]);
            const float n = fmaf(-2.0f, frcp(fexp2(v) + 1.0f), 1.0f);

            h  = fmaf(z, h - n, n);                    // evolves unconditionally
            hs = ((t0 + k) == len - 1) ? h : hs;       // off-chain save
        }
        c0 = n0; c1 = n1; n0 = f0; n1 = f1;
    }

    if (j < 3)
        out[batch * 3 + j] = frcp(fexp2(NL * hs) + 1.0f);
}

extern "C" void kernel_launch(void* const* d_in, const int* in_sizes, int n_in,
                              void* d_out, int out_size, void* d_ws, size_t ws_size,
                              hipStream_t stream) {
    const float* x    = (const float*)d_in[0];
    const int*   lens = (const int*)  d_in[1];
    const float* h0   = (const float*)d_in[2];
    const float* W_ih = (const float*)d_in[3];
    const float* W_hh = (const float*)d_in[4];
    const float* b_ih = (const float*)d_in[5];
    const float* b_hh = (const float*)d_in[6];
    float* out = (float*)d_out;

    const int B = in_sizes[1];              // seq_lengths is [B]
    const int T = in_sizes[0] / B;          // x is [B,T,1]

    gru_scan8<<<B / 16, 64, 0, stream>>>(x, lens, h0, W_ih, W_hh, b_ih, b_hh, out, B, T);
}